// Round 9
// baseline (388.110 us; speedup 1.0000x reference)
//
#include <hip/hip_runtime.h>

#define Nn 100000
#define Ee 600000
#define Fin 128
#define Hd  256
#define NB  ((Nn + 1023) / 1024)   // 98 scan blocks
#define CB  12500                  // convert blocks: Nn*Fin/4/256
#define PB  768                    // prep blocks
#define EB  ((Ee + 255) / 256)     // edge blocks

typedef __attribute__((ext_vector_type(8))) short short8;
typedef __attribute__((ext_vector_type(4))) float floatx4;

__device__ __forceinline__ float bf2f(unsigned short h) {
    return __uint_as_float(((unsigned int)h) << 16);
}
__device__ __forceinline__ unsigned short f2bf(float f) {
    unsigned int u = __float_as_uint(f);
    u += 0x7FFFu + ((u >> 16) & 1u);   // round-to-nearest-even
    return (unsigned short)(u >> 16);
}
__device__ __forceinline__ float loadf(const void* p, int i, int f32) {
    return f32 ? ((const float*)p)[i] : bf2f(((const unsigned short*)p)[i]);
}
__device__ __forceinline__ void gload_lds16(const void* g, void* lds) {
    __builtin_amdgcn_global_load_lds((const __attribute__((address_space(1))) void*)g,
                                     (__attribute__((address_space(3))) void*)lds,
                                     16, 0, 0);
}

__device__ __forceinline__ void get_edge(const int* __restrict__ ei, int is64, int e,
                                         int& s, int& d) {
    if (is64) { s = ei[2 * e]; d = ei[2 * (Ee + e)]; }
    else      { s = ei[e];     d = ei[Ee + e]; }
}

// ---- fused: runtime probes (wave-parallel, was ~10us serial chain) + cnt zero ----
__global__ void k_init(const unsigned int* __restrict__ ei,
                       const unsigned short* __restrict__ xu,
                       int* __restrict__ flag, int* __restrict__ cnt) {
    int i = blockIdx.x * 256 + threadIdx.x;
    if (i < 2 * Nn) cnt[i] = 0;            // cnt and cur are contiguous
    if (blockIdx.x == 0 && threadIdx.x < 64) {
        int l = threadIdx.x;
        unsigned hi = (l < 32) ? ei[2 * l + 1] : 0u;      // high halves of first 32 int64
        unsigned long long nz = __ballot(hi != 0u);
        int big = 0;
#pragma unroll
        for (int j = 0; j < 4; j++) {                     // even ushorts 0..510, same set as before
            unsigned u = xu[l * 8 + j * 2];
            if (((u >> 7) & 0xFFu) >= 0xC0u) big = 1;
        }
        unsigned long long bb = __ballot(big != 0);
        if (l == 0) { flag[0] = (nz == 0ull) ? 1 : 0; flag[1] = (bb != 0ull) ? 1 : 0; }
    }
}

// ---- fused: x->xb convert | weight pre-transpose | edge degree count ----
__global__ void k_pre(const void* __restrict__ x, unsigned short* __restrict__ xb,
                      const void* __restrict__ Wl1, const void* __restrict__ Wr1,
                      const void* __restrict__ Wl2, const void* __restrict__ Wr2,
                      unsigned short* __restrict__ Wt1, unsigned short* __restrict__ Wt2,
                      const int* __restrict__ ei, int* __restrict__ cnt,
                      const int* __restrict__ flag) {
    int bid = blockIdx.x;
    if (bid < CB) {
        int i = (bid * 256 + threadIdx.x) * 4;
        if (i >= Nn * Fin) return;
        if (flag[1]) {
            float4 v = ((const float4*)x)[i >> 2];
            ushort4 u;
            u.x = f2bf(v.x); u.y = f2bf(v.y); u.z = f2bf(v.z); u.w = f2bf(v.w);
            ((ushort4*)xb)[i >> 2] = u;
        } else {
            ((ushort4*)xb)[i >> 2] = ((const ushort4*)x)[i >> 2];
        }
    } else if (bid < CB + PB) {
        int f32 = flag[1];
        int tid = (bid - CB) * 256 + threadIdx.x;
        if (tid < 256 * 256) {
            int n = tid >> 8, k = tid & 255;
            float v = (k < 128) ? loadf(Wl1, k * 256 + n, f32) : loadf(Wr1, (k - 128) * 256 + n, f32);
            Wt1[n * 256 + k] = f2bf(v);
        }
        int t2 = tid - 256 * 256;
        if (t2 >= 0 && t2 < 256 * 512) {
            int n = t2 >> 9, k = t2 & 511;
            float v = (k < 256) ? loadf(Wl2, k * 256 + n, f32) : loadf(Wr2, (k - 256) * 256 + n, f32);
            Wt2[n * 512 + k] = f2bf(v);
        }
    } else {
        int e = (bid - CB - PB) * 256 + threadIdx.x;
        if (e >= Ee) return;
        int is64 = flag[0], s, d;
        get_edge(ei, is64, e, s, d);
        atomicAdd(&cnt[d], 1);
    }
}

// hierarchical scan: k_bsum -> k_bscan -> k_rowptr (all coalesced int4)
__global__ void k_bsum(const int* __restrict__ cnt, int* __restrict__ bsum) {
    __shared__ int red[256];
    int b = blockIdx.x, t = threadIdx.x;
    int i = b * 1024 + t * 4;
    int s = 0;
    if (i + 3 < Nn) {
        int4 v = *reinterpret_cast<const int4*>(cnt + i);
        s = v.x + v.y + v.z + v.w;
    } else {
        for (int j = 0; j < 4; j++) if (i + j < Nn) s += cnt[i + j];
    }
    red[t] = s;
    __syncthreads();
    for (int off = 128; off > 0; off >>= 1) {
        if (t < off) red[t] += red[t + off];
        __syncthreads();
    }
    if (t == 0) bsum[b] = red[0];
}

__global__ void k_bscan(const int* __restrict__ bsum, int* __restrict__ bpre,
                        int* __restrict__ rowptr) {
    __shared__ int sc[128];
    int t = threadIdx.x;
    int v = (t < NB) ? bsum[t] : 0;
    sc[t] = v;
    __syncthreads();
    for (int off = 1; off < 128; off <<= 1) {
        int add = (t >= off) ? sc[t - off] : 0;
        __syncthreads();
        sc[t] += add;
        __syncthreads();
    }
    if (t < NB) bpre[t] = sc[t] - v;          // exclusive prefix
    if (t == 127) rowptr[Nn] = sc[127];       // grand total (== Ee)
}

__global__ void k_rowptr(const int* __restrict__ cnt, const int* __restrict__ bpre,
                         int* __restrict__ rowptr) {
    __shared__ int sc[256];
    int b = blockIdx.x, t = threadIdx.x;
    int i = b * 1024 + t * 4;
    int4 c = make_int4(0, 0, 0, 0);
    if (i + 3 < Nn) {
        c = *reinterpret_cast<const int4*>(cnt + i);
    } else {
        if (i     < Nn) c.x = cnt[i];
        if (i + 1 < Nn) c.y = cnt[i + 1];
        if (i + 2 < Nn) c.z = cnt[i + 2];
        if (i + 3 < Nn) c.w = cnt[i + 3];
    }
    int s = c.x + c.y + c.z + c.w;
    sc[t] = s;
    __syncthreads();
    for (int off = 1; off < 256; off <<= 1) {
        int add = (t >= off) ? sc[t - off] : 0;
        __syncthreads();
        sc[t] += add;
        __syncthreads();
    }
    int p = bpre[b] + sc[t] - s;   // exclusive prefix of element i
    int4 r;
    r.x = p;
    r.y = r.x + c.x;
    r.z = r.y + c.y;
    r.w = r.z + c.z;
    if (i + 3 < Nn) {
        *reinterpret_cast<int4*>(rowptr + i) = r;
    } else {
        if (i     < Nn) rowptr[i]     = r.x;
        if (i + 1 < Nn) rowptr[i + 1] = r.y;
        if (i + 2 < Nn) rowptr[i + 2] = r.z;
        if (i + 3 < Nn) rowptr[i + 3] = r.w;
    }
}

__global__ void k_fill(const int* __restrict__ ei, const int* __restrict__ flag,
                       const int* __restrict__ rowptr, int* __restrict__ cur,
                       int* __restrict__ srcl) {
    int e = blockIdx.x * 256 + threadIdx.x;
    if (e >= Ee) return;
    int is64 = flag[0], s, d;
    get_edge(ei, is64, e, s, d);
    int pos = atomicAdd(&cur[d], 1);
    srcl[rowptr[d] + pos] = s;
}

// ---- gather-based mean aggregation: one wave per node, 8-deep MLP ----
template <int F, int SIN, int SOUT>
__device__ __forceinline__ void agg_body(const unsigned short* __restrict__ X,
                                         unsigned short* __restrict__ O,
                                         const int* __restrict__ rowptr,
                                         const int* __restrict__ srcl) {
    int gw = (blockIdx.x * blockDim.x + threadIdx.x) >> 6;
    int lane = threadIdx.x & 63;
    if (gw >= Nn) return;
    int b = rowptr[gw], e = rowptr[gw + 1];
    constexpr int C = F / 64;
    float acc[C] = {};
    if (e > b) {
        int last = e - 1;
        for (int i = b; i < e; i += 8) {
            int sv[8];
            float w[8];
#pragma unroll
            for (int j = 0; j < 8; j++) {
                int id = i + j;
                sv[j] = srcl[id < last ? id : last];
                w[j] = (id < e) ? 1.f : 0.f;
            }
            if constexpr (C == 2) {
                ushort2 u[8];
#pragma unroll
                for (int j = 0; j < 8; j++)
                    u[j] = *reinterpret_cast<const ushort2*>(X + (size_t)sv[j] * SIN + lane * 2);
#pragma unroll
                for (int j = 0; j < 8; j++) {
                    acc[0] = fmaf(w[j], bf2f(u[j].x), acc[0]);
                    acc[1] = fmaf(w[j], bf2f(u[j].y), acc[1]);
                }
            } else {
                ushort4 u[8];
#pragma unroll
                for (int j = 0; j < 8; j++)
                    u[j] = *reinterpret_cast<const ushort4*>(X + (size_t)sv[j] * SIN + lane * 4);
#pragma unroll
                for (int j = 0; j < 8; j++) {
                    acc[0] = fmaf(w[j], bf2f(u[j].x), acc[0]);
                    acc[1] = fmaf(w[j], bf2f(u[j].y), acc[1]);
                    acc[2] = fmaf(w[j], bf2f(u[j].z), acc[2]);
                    acc[3] = fmaf(w[j], bf2f(u[j].w), acc[3]);
                }
            }
        }
    }
    float inv = 1.f / (float)max(e - b, 1);
    unsigned short* op = O + (size_t)gw * SOUT + lane * C;
    if constexpr (C == 2) {
        ushort2 u; u.x = f2bf(acc[0] * inv); u.y = f2bf(acc[1] * inv);
        *reinterpret_cast<ushort2*>(op) = u;
    } else {
        ushort4 u;
        u.x = f2bf(acc[0] * inv); u.y = f2bf(acc[1] * inv);
        u.z = f2bf(acc[2] * inv); u.w = f2bf(acc[3] * inv);
        *reinterpret_cast<ushort4*>(op) = u;
    }
}

__global__ void k_agg1(const unsigned short* __restrict__ xb, unsigned short* __restrict__ agg1,
                       const int* __restrict__ rowptr, const int* __restrict__ srcl) {
    agg_body<Fin, Fin, Fin>(xb, agg1, rowptr, srcl);
}

__global__ void k_agg2(const int* __restrict__ rowptr, const int* __restrict__ srcl,
                       unsigned short* __restrict__ acat_ws) {
    agg_body<Hd, 512, 512>(acat_ws + 256, acat_ws, rowptr, srcl);
}

// ---- MFMA GEMM core: TRIPLE-buffered BK=64 with counted vmcnt (T3+T4) ----
// Prior attempts (R3/R7) kept prefetch depth 1 + full drain at each tile ->
// neutral (m218: drain0 == no-prefetch). This is the real recipe: depth-2
// prefetch, vmcnt(6) counted wait (tile t+1's 6 loads stay IN FLIGHT across
// the barrier), ONE raw s_barrier per tile. LDS = 3 x 48 KB = 144 KB ->
// 1 block/CU: intra-block pipelining replaces TLP (m201 trade, 128KB precedent).
// Race safety: STAGE(t+2) writes slot (t+2)%3 == (t-1)%3, whose readers
// (tile t-1 compute) all passed this tile's barrier. Slot t%3 readiness:
// each wave's own vmcnt(6) + barrier join (Y at barrier => Y's vmcnt passed).
template <int KT, int K1, int S1, int S2>
__device__ __forceinline__ void gemm_core_tri(const unsigned short* __restrict__ A1,
                                              const unsigned short* __restrict__ A2,
                                              const unsigned short* __restrict__ Wt,
                                              floatx4 (&acc)[4][4],
                                              unsigned short* sA, unsigned short* sB,
                                              int m_base) {
    const int tid = threadIdx.x;
    const int lane = tid & 63, wid = tid >> 6;
    const int wm = wid & 1, wn = wid >> 1;
    const int quad = lane >> 4, l16 = lane & 15;
    const int n_base = wn * 64;
    const int rs = tid >> 3;       // row-octet owner
    const int cs = tid & 7;        // k-chunk slot (8 shorts)
    constexpr int NT = KT / 64;

#define STAGE(t, buf)                                                              \
    {                                                                              \
        int kb_ = (t) * 64;                                                        \
        _Pragma("unroll")                                                          \
        for (int i_ = 0; i_ < 2; i_++) {                                           \
            int r_ = i_ * 64 + rs;                                                 \
            int gk_ = kb_ + ((cs ^ (r_ & 7)) << 3);                                \
            int m_ = m_base + r_; if (m_ >= Nn) m_ = Nn - 1;                       \
            const unsigned short* gp_ = (gk_ < K1)                                 \
                ? A1 + (size_t)m_ * S1 + gk_                                       \
                : A2 + (size_t)m_ * S2 + (gk_ - K1);                               \
            gload_lds16(gp_, sA + (buf) * 8192 + i_ * 4096 + wid * 512);           \
        }                                                                          \
        _Pragma("unroll")                                                          \
        for (int i_ = 0; i_ < 4; i_++) {                                           \
            int n_ = i_ * 64 + rs;                                                 \
            int gk_ = kb_ + ((cs ^ (n_ & 7)) << 3);                                \
            gload_lds16(Wt + (size_t)n_ * KT + gk_,                                \
                        sB + (buf) * 16384 + i_ * 4096 + wid * 512);               \
        }                                                                          \
    }

#define COMPUTE(buf)                                                               \
    _Pragma("unroll")                                                              \
    for (int ks_ = 0; ks_ < 64; ks_ += 32) {                                       \
        short8 a_[4], b_[4];                                                       \
        int q_ = (ks_ >> 3) + quad;                                                \
        _Pragma("unroll")                                                          \
        for (int mt_ = 0; mt_ < 4; mt_++) {                                        \
            int r_ = wm * 64 + mt_ * 16 + l16;                                     \
            a_[mt_] = *reinterpret_cast<const short8*>(                            \
                sA + (buf) * 8192 + r_ * 64 + ((q_ ^ (l16 & 7)) << 3));            \
        }                                                                          \
        _Pragma("unroll")                                                          \
        for (int nt_ = 0; nt_ < 4; nt_++) {                                        \
            int n_ = n_base + nt_ * 16 + l16;                                      \
            b_[nt_] = *reinterpret_cast<const short8*>(                            \
                sB + (buf) * 16384 + n_ * 64 + ((q_ ^ (l16 & 7)) << 3));           \
        }                                                                          \
        _Pragma("unroll")                                                          \
        for (int mt_ = 0; mt_ < 4; mt_++)                                          \
            _Pragma("unroll")                                                      \
            for (int nt_ = 0; nt_ < 4; nt_++)                                      \
                acc[mt_][nt_] = __builtin_amdgcn_mfma_f32_16x16x32_bf16(           \
                    a_[mt_], b_[nt_], acc[mt_][nt_], 0, 0, 0);                     \
    }

    STAGE(0, 0)
    STAGE(1, 1)
#pragma unroll
    for (int t = 0; t < NT; t++) {
        if (t + 1 < NT) {
            asm volatile("s_waitcnt vmcnt(6)" ::: "memory");   // tile t landed; t+1's 6 stay in flight
        } else {
            asm volatile("s_waitcnt vmcnt(0)" ::: "memory");   // last tile: nothing beyond
        }
        __builtin_amdgcn_sched_barrier(0);
        asm volatile("s_barrier" ::: "memory");                // all waves: t ready, t-1 reads done
        __builtin_amdgcn_sched_barrier(0);
        if (t + 2 < NT) STAGE(t + 2, (t + 2) % 3)              // into slot freed by tile t-1
        COMPUTE(t % 3)
    }
#undef STAGE
#undef COMPUTE
}

// layer 1: h = relu([agg1|xb] @ Wt1 + b1) -> Acat[:,256:512) (bf16)
// Coalesced epilogue via 32 KB LDS bounce (sB slot 0 reused).
__global__ __launch_bounds__(512) void k_gemm1(const unsigned short* __restrict__ agg1,
                                               const unsigned short* __restrict__ xb,
                                               const unsigned short* __restrict__ Wt1,
                                               const void* __restrict__ bias,
                                               const int* __restrict__ flag,
                                               unsigned short* __restrict__ acat_ws) {
    __shared__ unsigned short sA[24576];   // 3 x 16 KB
    __shared__ unsigned short sB[49152];   // 3 x 32 KB
    int f32 = flag[1];
    int tid = threadIdx.x;
    int wid = tid >> 6, lane = tid & 63;
    int wm = wid & 1, wn = wid >> 1;
    int quad = lane >> 4, l16 = lane & 15;
    int m_base = blockIdx.x * 128;
    floatx4 acc[4][4] = {};
    gemm_core_tri<256, 128, 128, 128>(agg1, xb, Wt1, acc, sA, sB, m_base);
#pragma unroll
    for (int p = 0; p < 2; p++) {
        __syncthreads();                       // sB slot free (all reads drained)
        if (wm == p) {
#pragma unroll
            for (int nt = 0; nt < 4; nt++) {
                int n = wn * 64 + nt * 16 + l16;
                float bv = loadf(bias, n, f32);
#pragma unroll
                for (int mt = 0; mt < 4; mt++) {
#pragma unroll
                    for (int r = 0; r < 4; r++) {
                        float v = acc[mt][nt][r] + bv;
                        v = v > 0.f ? v : 0.f;
                        sB[(mt * 16 + quad * 4 + r) * 256 + n] = f2bf(v);
                    }
                }
            }
        }
        __syncthreads();
#pragma unroll
        for (int rnd = 0; rnd < 4; rnd++) {
            int rl = rnd * 16 + (tid >> 5);
            int m = m_base + p * 64 + rl;
            if (m < Nn)
                *reinterpret_cast<short8*>(acat_ws + (size_t)m * 512 + 256 + (tid & 31) * 8) =
                    *reinterpret_cast<const short8*>(sB + rl * 256 + (tid & 31) * 8);
        }
    }
}

// layer 2: out = [agg2|h] @ Wt2 + b2. Acat row = [agg|h] contiguous 512-k
// stream, so K1=512 makes the A2 branch compile-time dead.
__global__ __launch_bounds__(512) void k_gemm2(const unsigned short* __restrict__ Wt2,
                                               const void* __restrict__ bias,
                                               const int* __restrict__ flag,
                                               const unsigned short* __restrict__ acat_ws,
                                               void* __restrict__ out) {
    __shared__ unsigned short sA[24576];
    __shared__ unsigned short sB[49152];
    int f32 = flag[1];
    int tid = threadIdx.x;
    int wid = tid >> 6, lane = tid & 63;
    int wm = wid & 1, wn = wid >> 1;
    int quad = lane >> 4, l16 = lane & 15;
    int m_base = blockIdx.x * 128;
    floatx4 acc[4][4] = {};
    gemm_core_tri<512, 512, 512, 512>(acat_ws, acat_ws, Wt2, acc, sA, sB, m_base);
    float* sF = (float*)sB;                    // 32 rows x 256 f32 = 32 KB
#pragma unroll
    for (int q = 0; q < 4; q++) {
        __syncthreads();
        if (wm == (q >> 1)) {
#pragma unroll
            for (int nt = 0; nt < 4; nt++) {
                int n = wn * 64 + nt * 16 + l16;
                float bv = loadf(bias, n, f32);
#pragma unroll
                for (int mt2 = 0; mt2 < 2; mt2++) {
                    int mt = (q & 1) * 2 + mt2;
#pragma unroll
                    for (int r = 0; r < 4; r++)
                        sF[(mt2 * 16 + quad * 4 + r) * 256 + n] = acc[mt][nt][r] + bv;
                }
            }
        }
        __syncthreads();
#pragma unroll
        for (int rnd = 0; rnd < 2; rnd++) {
            int rl = rnd * 16 + (tid >> 5);
            int m = m_base + q * 32 + rl;
            if (m < Nn) {
                if (f32) {
                    float4* dst = (float4*)((float*)out + (size_t)m * 256) + (tid & 31) * 2;
                    const float4* src = (const float4*)(sF + rl * 256) + (tid & 31) * 2;
                    dst[0] = src[0];
                    dst[1] = src[1];
                } else {
                    const float* src = sF + rl * 256 + (tid & 31) * 8;
                    short8 pk;
#pragma unroll
                    for (int j = 0; j < 8; j++)
                        ((unsigned short*)&pk)[j] = f2bf(src[j]);
                    *reinterpret_cast<short8*>((unsigned short*)out + (size_t)m * 256 + (tid & 31) * 8) = pk;
                }
            }
        }
    }
}

extern "C" void kernel_launch(void* const* d_in, const int* in_sizes, int n_in,
                              void* d_out, int out_size, void* d_ws, size_t ws_size,
                              hipStream_t stream) {
    const void* x   = d_in[0];
    const int*  ei  = (const int*)d_in[1];
    const void* Wl1 = d_in[2];
    const void* Wr1 = d_in[3];
    const void* b1  = d_in[4];
    const void* Wl2 = d_in[5];
    const void* Wr2 = d_in[6];
    const void* b2  = d_in[7];

    char* ws = (char*)d_ws;
    size_t off_cnt    = 0;
    size_t off_cur    = off_cnt + (size_t)Nn * 4;
    size_t off_rowptr = off_cur + (size_t)Nn * 4;
    size_t off_srcl   = off_rowptr + (size_t)(Nn + 4) * 4;
    size_t off_flag   = off_srcl + (size_t)Ee * 4;
    size_t off_bsum   = ((off_flag + 8 + 255) / 256) * 256;   // NB ints
    size_t off_bpre   = off_bsum + 128 * 4;                   // NB ints
    size_t off_wt1    = off_bpre + 128 * 4;
    size_t off_wt2    = off_wt1 + 256 * 256 * 2;
    size_t off_xb     = off_wt2 + 256 * 512 * 2;
    size_t off_agg1   = off_xb + (size_t)Nn * Fin * 2;
    size_t off_acat   = off_agg1 + (size_t)Nn * Fin * 2;

    int*            cnt     = (int*)(ws + off_cnt);
    int*            cur     = (int*)(ws + off_cur);
    int*            rowptr  = (int*)(ws + off_rowptr);
    int*            srcl    = (int*)(ws + off_srcl);
    int*            flag    = (int*)(ws + off_flag);
    int*            bsum    = (int*)(ws + off_bsum);
    int*            bpre    = (int*)(ws + off_bpre);
    unsigned short* Wt1     = (unsigned short*)(ws + off_wt1);
    unsigned short* Wt2     = (unsigned short*)(ws + off_wt2);
    unsigned short* xb      = (unsigned short*)(ws + off_xb);
    unsigned short* agg1    = (unsigned short*)(ws + off_agg1);
    unsigned short* acat_ws = (unsigned short*)(ws + off_acat);

    k_init<<<(2 * Nn + 255) / 256, 256, 0, stream>>>((const unsigned int*)ei,
                                                     (const unsigned short*)x, flag, cnt);
    k_pre<<<CB + PB + EB, 256, 0, stream>>>(x, xb, Wl1, Wr1, Wl2, Wr2, Wt1, Wt2,
                                            ei, cnt, flag);
    k_bsum<<<NB, 256, 0, stream>>>(cnt, bsum);
    k_bscan<<<1, 128, 0, stream>>>(bsum, bpre, rowptr);
    k_rowptr<<<NB, 256, 0, stream>>>(cnt, bpre, rowptr);
    k_fill<<<EB, 256, 0, stream>>>(ei, flag, rowptr, cur, srcl);

    int ab = (Nn * 64 + 255) / 256;
    int gx = (Nn + 127) / 128;

    k_agg1<<<ab, 256, 0, stream>>>(xb, agg1, rowptr, srcl);
    k_gemm1<<<gx, 512, 0, stream>>>(agg1, xb, Wt1, b1, flag, acat_ws);
    k_agg2<<<ab, 256, 0, stream>>>(rowptr, srcl, acat_ws);
    k_gemm2<<<gx, 512, 0, stream>>>(Wt2, b2, flag, acat_ws, d_out);
}

// Round 10
// 387.064 us; speedup vs baseline: 1.0027x; 1.0027x over previous
//
#include <hip/hip_runtime.h>

#define Nn 100000
#define Ee 600000
#define Fin 128
#define Hd  256
#define NB  ((Nn + 1023) / 1024)   // 98 scan blocks
#define CB  12500                  // convert blocks: Nn*Fin/4/256
#define PB  768                    // prep blocks
#define EB  ((Ee + 255) / 256)     // edge blocks

typedef __attribute__((ext_vector_type(8))) short short8;
typedef __attribute__((ext_vector_type(4))) float floatx4;

__device__ __forceinline__ float bf2f(unsigned short h) {
    return __uint_as_float(((unsigned int)h) << 16);
}
__device__ __forceinline__ unsigned short f2bf(float f) {
    unsigned int u = __float_as_uint(f);
    u += 0x7FFFu + ((u >> 16) & 1u);   // round-to-nearest-even
    return (unsigned short)(u >> 16);
}
__device__ __forceinline__ float loadf(const void* p, int i, int f32) {
    return f32 ? ((const float*)p)[i] : bf2f(((const unsigned short*)p)[i]);
}
__device__ __forceinline__ void gload_lds16(const void* g, void* lds) {
    __builtin_amdgcn_global_load_lds((const __attribute__((address_space(1))) void*)g,
                                     (__attribute__((address_space(3))) void*)lds,
                                     16, 0, 0);
}

__device__ __forceinline__ void get_edge(const int* __restrict__ ei, int is64, int e,
                                         int& s, int& d) {
    if (is64) { s = ei[2 * e]; d = ei[2 * (Ee + e)]; }
    else      { s = ei[e];     d = ei[Ee + e]; }
}

// ---- fused: runtime probes (wave-parallel) + cnt/cur zero ----
__global__ void k_init(const unsigned int* __restrict__ ei,
                       const unsigned short* __restrict__ xu,
                       int* __restrict__ flag, int* __restrict__ cnt) {
    int i = blockIdx.x * 256 + threadIdx.x;
    if (i < 2 * Nn) cnt[i] = 0;            // cnt and cur are contiguous
    if (blockIdx.x == 0 && threadIdx.x < 64) {
        int l = threadIdx.x;
        unsigned hi = (l < 32) ? ei[2 * l + 1] : 0u;      // high halves of first 32 int64
        unsigned long long nz = __ballot(hi != 0u);
        int big = 0;
#pragma unroll
        for (int j = 0; j < 4; j++) {                     // even ushorts 0..510
            unsigned u = xu[l * 8 + j * 2];
            if (((u >> 7) & 0xFFu) >= 0xC0u) big = 1;
        }
        unsigned long long bb = __ballot(big != 0);
        if (l == 0) { flag[0] = (nz == 0ull) ? 1 : 0; flag[1] = (bb != 0ull) ? 1 : 0; }
    }
}

// ---- fused: x->xb convert | weight pre-transpose | edge degree count ----
__global__ void k_pre(const void* __restrict__ x, unsigned short* __restrict__ xb,
                      const void* __restrict__ Wl1, const void* __restrict__ Wr1,
                      const void* __restrict__ Wl2, const void* __restrict__ Wr2,
                      unsigned short* __restrict__ Wt1, unsigned short* __restrict__ Wt2,
                      const int* __restrict__ ei, int* __restrict__ cnt,
                      const int* __restrict__ flag) {
    int bid = blockIdx.x;
    if (bid < CB) {
        int i = (bid * 256 + threadIdx.x) * 4;
        if (i >= Nn * Fin) return;
        if (flag[1]) {
            float4 v = ((const float4*)x)[i >> 2];
            ushort4 u;
            u.x = f2bf(v.x); u.y = f2bf(v.y); u.z = f2bf(v.z); u.w = f2bf(v.w);
            ((ushort4*)xb)[i >> 2] = u;
        } else {
            ((ushort4*)xb)[i >> 2] = ((const ushort4*)x)[i >> 2];
        }
    } else if (bid < CB + PB) {
        int f32 = flag[1];
        int tid = (bid - CB) * 256 + threadIdx.x;
        if (tid < 256 * 256) {
            int n = tid >> 8, k = tid & 255;
            float v = (k < 128) ? loadf(Wl1, k * 256 + n, f32) : loadf(Wr1, (k - 128) * 256 + n, f32);
            Wt1[n * 256 + k] = f2bf(v);
        }
        int t2 = tid - 256 * 256;
        if (t2 >= 0 && t2 < 256 * 512) {
            int n = t2 >> 9, k = t2 & 511;
            float v = (k < 256) ? loadf(Wl2, k * 256 + n, f32) : loadf(Wr2, (k - 256) * 256 + n, f32);
            Wt2[n * 512 + k] = f2bf(v);
        }
    } else {
        int e = (bid - CB - PB) * 256 + threadIdx.x;
        if (e >= Ee) return;
        int is64 = flag[0], s, d;
        get_edge(ei, is64, e, s, d);
        atomicAdd(&cnt[d], 1);
    }
}

// hierarchical scan: k_bsum -> k_bscan -> k_rowptr (all coalesced int4)
__global__ void k_bsum(const int* __restrict__ cnt, int* __restrict__ bsum) {
    __shared__ int red[256];
    int b = blockIdx.x, t = threadIdx.x;
    int i = b * 1024 + t * 4;
    int s = 0;
    if (i + 3 < Nn) {
        int4 v = *reinterpret_cast<const int4*>(cnt + i);
        s = v.x + v.y + v.z + v.w;
    } else {
        for (int j = 0; j < 4; j++) if (i + j < Nn) s += cnt[i + j];
    }
    red[t] = s;
    __syncthreads();
    for (int off = 128; off > 0; off >>= 1) {
        if (t < off) red[t] += red[t + off];
        __syncthreads();
    }
    if (t == 0) bsum[b] = red[0];
}

__global__ void k_bscan(const int* __restrict__ bsum, int* __restrict__ bpre,
                        int* __restrict__ rowptr) {
    __shared__ int sc[128];
    int t = threadIdx.x;
    int v = (t < NB) ? bsum[t] : 0;
    sc[t] = v;
    __syncthreads();
    for (int off = 1; off < 128; off <<= 1) {
        int add = (t >= off) ? sc[t - off] : 0;
        __syncthreads();
        sc[t] += add;
        __syncthreads();
    }
    if (t < NB) bpre[t] = sc[t] - v;          // exclusive prefix
    if (t == 127) rowptr[Nn] = sc[127];       // grand total (== Ee)
}

__global__ void k_rowptr(const int* __restrict__ cnt, const int* __restrict__ bpre,
                         int* __restrict__ rowptr) {
    __shared__ int sc[256];
    int b = blockIdx.x, t = threadIdx.x;
    int i = b * 1024 + t * 4;
    int4 c = make_int4(0, 0, 0, 0);
    if (i + 3 < Nn) {
        c = *reinterpret_cast<const int4*>(cnt + i);
    } else {
        if (i     < Nn) c.x = cnt[i];
        if (i + 1 < Nn) c.y = cnt[i + 1];
        if (i + 2 < Nn) c.z = cnt[i + 2];
        if (i + 3 < Nn) c.w = cnt[i + 3];
    }
    int s = c.x + c.y + c.z + c.w;
    sc[t] = s;
    __syncthreads();
    for (int off = 1; off < 256; off <<= 1) {
        int add = (t >= off) ? sc[t - off] : 0;
        __syncthreads();
        sc[t] += add;
        __syncthreads();
    }
    int p = bpre[b] + sc[t] - s;   // exclusive prefix of element i
    int4 r;
    r.x = p;
    r.y = r.x + c.x;
    r.z = r.y + c.y;
    r.w = r.z + c.z;
    if (i + 3 < Nn) {
        *reinterpret_cast<int4*>(rowptr + i) = r;
    } else {
        if (i     < Nn) rowptr[i]     = r.x;
        if (i + 1 < Nn) rowptr[i + 1] = r.y;
        if (i + 2 < Nn) rowptr[i + 2] = r.z;
        if (i + 3 < Nn) rowptr[i + 3] = r.w;
    }
}

__global__ void k_fill(const int* __restrict__ ei, const int* __restrict__ flag,
                       const int* __restrict__ rowptr, int* __restrict__ cur,
                       int* __restrict__ srcl) {
    int e = blockIdx.x * 256 + threadIdx.x;
    if (e >= Ee) return;
    int is64 = flag[0], s, d;
    get_edge(ei, is64, e, s, d);
    int pos = atomicAdd(&cur[d], 1);
    srcl[rowptr[d] + pos] = s;
}

// ---- gather-based mean aggregation: one wave per node, 8-deep MLP ----
template <int F, int SIN, int SOUT>
__device__ __forceinline__ void agg_body(const unsigned short* __restrict__ X,
                                         unsigned short* __restrict__ O,
                                         const int* __restrict__ rowptr,
                                         const int* __restrict__ srcl) {
    int gw = (blockIdx.x * blockDim.x + threadIdx.x) >> 6;
    int lane = threadIdx.x & 63;
    if (gw >= Nn) return;
    int b = rowptr[gw], e = rowptr[gw + 1];
    constexpr int C = F / 64;
    float acc[C] = {};
    if (e > b) {
        int last = e - 1;
        for (int i = b; i < e; i += 8) {
            int sv[8];
            float w[8];
#pragma unroll
            for (int j = 0; j < 8; j++) {
                int id = i + j;
                sv[j] = srcl[id < last ? id : last];
                w[j] = (id < e) ? 1.f : 0.f;
            }
            if constexpr (C == 2) {
                ushort2 u[8];
#pragma unroll
                for (int j = 0; j < 8; j++)
                    u[j] = *reinterpret_cast<const ushort2*>(X + (size_t)sv[j] * SIN + lane * 2);
#pragma unroll
                for (int j = 0; j < 8; j++) {
                    acc[0] = fmaf(w[j], bf2f(u[j].x), acc[0]);
                    acc[1] = fmaf(w[j], bf2f(u[j].y), acc[1]);
                }
            } else {
                ushort4 u[8];
#pragma unroll
                for (int j = 0; j < 8; j++)
                    u[j] = *reinterpret_cast<const ushort4*>(X + (size_t)sv[j] * SIN + lane * 4);
#pragma unroll
                for (int j = 0; j < 8; j++) {
                    acc[0] = fmaf(w[j], bf2f(u[j].x), acc[0]);
                    acc[1] = fmaf(w[j], bf2f(u[j].y), acc[1]);
                    acc[2] = fmaf(w[j], bf2f(u[j].z), acc[2]);
                    acc[3] = fmaf(w[j], bf2f(u[j].w), acc[3]);
                }
            }
        }
    }
    float inv = 1.f / (float)max(e - b, 1);
    unsigned short* op = O + (size_t)gw * SOUT + lane * C;
    if constexpr (C == 2) {
        ushort2 u; u.x = f2bf(acc[0] * inv); u.y = f2bf(acc[1] * inv);
        *reinterpret_cast<ushort2*>(op) = u;
    } else {
        ushort4 u;
        u.x = f2bf(acc[0] * inv); u.y = f2bf(acc[1] * inv);
        u.z = f2bf(acc[2] * inv); u.w = f2bf(acc[3] * inv);
        *reinterpret_cast<ushort4*>(op) = u;
    }
}

__global__ void k_agg1(const unsigned short* __restrict__ xb, unsigned short* __restrict__ agg1,
                       const int* __restrict__ rowptr, const int* __restrict__ srcl) {
    agg_body<Fin, Fin, Fin>(xb, agg1, rowptr, srcl);
}

__global__ void k_agg2(const int* __restrict__ rowptr, const int* __restrict__ srcl,
                       unsigned short* __restrict__ acat_ws) {
    agg_body<Hd, 512, 512>(acat_ws + 256, acat_ws, rowptr, srcl);
}

// ---- MFMA GEMM core: BM=128 x BN=128, 256 threads (4 waves), BK=64,
// single-buffered, 2 barriers/kb (R8-proven schedule; pipelining nulled 3x).
// 32 KB LDS -> 5 blocks/CU (was 3) and grid 2x -> tail 14/782 -> 28/1564.
// Wave-uniform gload_lds dest; K-loop swizzle = measured-conflict-free R5 form.
template <int KT, int K1, int S1, int S2>
__device__ __forceinline__ void gemm_core_lds(const unsigned short* __restrict__ A1,
                                              const unsigned short* __restrict__ A2,
                                              const unsigned short* __restrict__ Wt,
                                              floatx4 (&acc)[4][4],
                                              unsigned short* sA, unsigned short* sB,
                                              int m_base) {
    const int tid = threadIdx.x;
    const int lane = tid & 63, wid = tid >> 6;       // 4 waves
    const int wm = wid & 1, wn = wid >> 1;           // 2x2 wave grid
    const int quad = lane >> 4, l16 = lane & 15;
    const int rs2 = lane >> 3;                       // row-in-wave-group 0..7
    const int cs = lane & 7;                         // k-chunk slot (8 shorts)

    for (int kb = 0; kb < KT; kb += 64) {
        __syncthreads();
        // stage A: 128 rows x 64 k (16 KB), 4 rounds of 32 rows
#pragma unroll
        for (int i = 0; i < 4; i++) {
            int r = i * 32 + wid * 8 + rs2;
            int gk = kb + ((cs ^ (r & 7)) << 3);
            int m = m_base + r; if (m >= Nn) m = Nn - 1;
            const unsigned short* gp = (gk < K1)
                ? A1 + (size_t)m * S1 + gk
                : A2 + (size_t)m * S2 + (gk - K1);
            gload_lds16(gp, sA + i * 2048 + wid * 512);
        }
        // stage B: 128 rows x 64 k (16 KB), same scheme (Wt pre-offset to n-panel)
#pragma unroll
        for (int i = 0; i < 4; i++) {
            int n = i * 32 + wid * 8 + rs2;
            int gk = kb + ((cs ^ (n & 7)) << 3);
            gload_lds16(Wt + (size_t)n * KT + gk, sB + i * 2048 + wid * 512);
        }
        __syncthreads();
#pragma unroll
        for (int ks = 0; ks < 64; ks += 32) {
            short8 a[4], b[4];
            int q = (ks >> 3) + quad;
#pragma unroll
            for (int mt = 0; mt < 4; mt++) {
                int r = wm * 64 + mt * 16 + l16;
                a[mt] = *reinterpret_cast<const short8*>(
                    sA + r * 64 + ((q ^ (l16 & 7)) << 3));
            }
#pragma unroll
            for (int nt = 0; nt < 4; nt++) {
                int n = wn * 64 + nt * 16 + l16;
                b[nt] = *reinterpret_cast<const short8*>(
                    sB + n * 64 + ((q ^ (l16 & 7)) << 3));
            }
#pragma unroll
            for (int mt = 0; mt < 4; mt++)
#pragma unroll
                for (int nt = 0; nt < 4; nt++)
                    acc[mt][nt] = __builtin_amdgcn_mfma_f32_16x16x32_bf16(a[mt], b[nt], acc[mt][nt], 0, 0, 0);
        }
    }
}

// layer 1: h = relu([agg1|xb] @ Wt1 + b1) -> Acat[:,256:512) (bf16)
// 128x128 tile; coalesced epilogue via 16 KB LDS bounce (sB reused), 2 passes.
__global__ __launch_bounds__(256) void k_gemm1(const unsigned short* __restrict__ agg1,
                                               const unsigned short* __restrict__ xb,
                                               const unsigned short* __restrict__ Wt1,
                                               const void* __restrict__ bias,
                                               const int* __restrict__ flag,
                                               unsigned short* __restrict__ acat_ws) {
    __shared__ unsigned short sA[8192];
    __shared__ unsigned short sB[8192];
    int f32 = flag[1];
    int tid = threadIdx.x;
    int wid = tid >> 6, lane = tid & 63;
    int wm = wid & 1, wn = wid >> 1;
    int quad = lane >> 4, l16 = lane & 15;
    int mb = blockIdx.x >> 1, nb = blockIdx.x & 1;   // pair shares A-tile (L2)
    int m_base = mb * 128;
    floatx4 acc[4][4] = {};
    gemm_core_lds<256, 128, 128, 128>(agg1, xb, Wt1 + (size_t)nb * 128 * 256,
                                      acc, sA, sB, m_base);
#pragma unroll
    for (int p = 0; p < 2; p++) {
        __syncthreads();                       // sB free
        if (wm == p) {
#pragma unroll
            for (int nt = 0; nt < 4; nt++) {
                int n = wn * 64 + nt * 16 + l16;               // 0..127
                float bv = loadf(bias, nb * 128 + n, f32);
#pragma unroll
                for (int mt = 0; mt < 4; mt++) {
#pragma unroll
                    for (int r = 0; r < 4; r++) {
                        float v = acc[mt][nt][r] + bv;
                        v = v > 0.f ? v : 0.f;
                        sB[(mt * 16 + quad * 4 + r) * 128 + n] = f2bf(v);
                    }
                }
            }
        }
        __syncthreads();
#pragma unroll
        for (int rnd = 0; rnd < 4; rnd++) {
            int rl = rnd * 16 + (tid >> 4);
            int m = m_base + p * 64 + rl;
            if (m < Nn)
                *reinterpret_cast<short8*>(acat_ws + (size_t)m * 512 + 256 + nb * 128 + (tid & 15) * 8) =
                    *reinterpret_cast<const short8*>(sB + rl * 128 + (tid & 15) * 8);
        }
    }
}

// layer 2: out = [agg2|h] @ Wt2 + b2. 128x128 tile; f32 epilogue bounce uses
// sA+sB as one 32 KB buffer (64 rows x 128 f32), 2 passes.
__global__ __launch_bounds__(256) void k_gemm2(const unsigned short* __restrict__ Wt2,
                                               const void* __restrict__ bias,
                                               const int* __restrict__ flag,
                                               const unsigned short* __restrict__ acat_ws,
                                               void* __restrict__ out) {
    __shared__ unsigned short sMem[16384];     // sA = sMem, sB = sMem+8192
    unsigned short* sA = sMem;
    unsigned short* sB = sMem + 8192;
    int f32 = flag[1];
    int tid = threadIdx.x;
    int wid = tid >> 6, lane = tid & 63;
    int wm = wid & 1, wn = wid >> 1;
    int quad = lane >> 4, l16 = lane & 15;
    int mb = blockIdx.x >> 1, nb = blockIdx.x & 1;
    int m_base = mb * 128;
    floatx4 acc[4][4] = {};
    gemm_core_lds<512, 512, 512, 512>(acat_ws, acat_ws, Wt2 + (size_t)nb * 128 * 512,
                                      acc, sA, sB, m_base);
    float* sF = (float*)sMem;                  // 64 rows x 128 f32 = 32 KB
#pragma unroll
    for (int p = 0; p < 2; p++) {
        __syncthreads();
        if (wm == p) {
#pragma unroll
            for (int nt = 0; nt < 4; nt++) {
                int n = wn * 64 + nt * 16 + l16;
                float bv = loadf(bias, nb * 128 + n, f32);
#pragma unroll
                for (int mt = 0; mt < 4; mt++) {
#pragma unroll
                    for (int r = 0; r < 4; r++)
                        sF[(mt * 16 + quad * 4 + r) * 128 + n] = acc[mt][nt][r] + bv;
                }
            }
        }
        __syncthreads();
#pragma unroll
        for (int rnd = 0; rnd < 8; rnd++) {
            int rl = rnd * 8 + (tid >> 5);
            int m = m_base + p * 64 + rl;
            if (m < Nn) {
                if (f32) {
                    *((float4*)((float*)out + (size_t)m * 256 + nb * 128) + (tid & 31)) =
                        *((const float4*)(sF + rl * 128) + (tid & 31));
                } else {
                    const float* src = sF + rl * 128 + (tid & 31) * 4;
                    ushort4 pk;
                    pk.x = f2bf(src[0]); pk.y = f2bf(src[1]);
                    pk.z = f2bf(src[2]); pk.w = f2bf(src[3]);
                    *reinterpret_cast<ushort4*>((unsigned short*)out + (size_t)m * 256 + nb * 128 + (tid & 31) * 4) = pk;
                }
            }
        }
    }
}

extern "C" void kernel_launch(void* const* d_in, const int* in_sizes, int n_in,
                              void* d_out, int out_size, void* d_ws, size_t ws_size,
                              hipStream_t stream) {
    const void* x   = d_in[0];
    const int*  ei  = (const int*)d_in[1];
    const void* Wl1 = d_in[2];
    const void* Wr1 = d_in[3];
    const void* b1  = d_in[4];
    const void* Wl2 = d_in[5];
    const void* Wr2 = d_in[6];
    const void* b2  = d_in[7];

    char* ws = (char*)d_ws;
    size_t off_cnt    = 0;
    size_t off_cur    = off_cnt + (size_t)Nn * 4;
    size_t off_rowptr = off_cur + (size_t)Nn * 4;
    size_t off_srcl   = off_rowptr + (size_t)(Nn + 4) * 4;
    size_t off_flag   = off_srcl + (size_t)Ee * 4;
    size_t off_bsum   = ((off_flag + 8 + 255) / 256) * 256;   // NB ints
    size_t off_bpre   = off_bsum + 128 * 4;                   // NB ints
    size_t off_wt1    = off_bpre + 128 * 4;
    size_t off_wt2    = off_wt1 + 256 * 256 * 2;
    size_t off_xb     = off_wt2 + 256 * 512 * 2;
    size_t off_agg1   = off_xb + (size_t)Nn * Fin * 2;
    size_t off_acat   = off_agg1 + (size_t)Nn * Fin * 2;

    int*            cnt     = (int*)(ws + off_cnt);
    int*            cur     = (int*)(ws + off_cur);
    int*            rowptr  = (int*)(ws + off_rowptr);
    int*            srcl    = (int*)(ws + off_srcl);
    int*            flag    = (int*)(ws + off_flag);
    int*            bsum    = (int*)(ws + off_bsum);
    int*            bpre    = (int*)(ws + off_bpre);
    unsigned short* Wt1     = (unsigned short*)(ws + off_wt1);
    unsigned short* Wt2     = (unsigned short*)(ws + off_wt2);
    unsigned short* xb      = (unsigned short*)(ws + off_xb);
    unsigned short* agg1    = (unsigned short*)(ws + off_agg1);
    unsigned short* acat_ws = (unsigned short*)(ws + off_acat);

    k_init<<<(2 * Nn + 255) / 256, 256, 0, stream>>>((const unsigned int*)ei,
                                                     (const unsigned short*)x, flag, cnt);
    k_pre<<<CB + PB + EB, 256, 0, stream>>>(x, xb, Wl1, Wr1, Wl2, Wr2, Wt1, Wt2,
                                            ei, cnt, flag);
    k_bsum<<<NB, 256, 0, stream>>>(cnt, bsum);
    k_bscan<<<1, 128, 0, stream>>>(bsum, bpre, rowptr);
    k_rowptr<<<NB, 256, 0, stream>>>(cnt, bpre, rowptr);
    k_fill<<<EB, 256, 0, stream>>>(ei, flag, rowptr, cur, srcl);

    int ab = (Nn * 64 + 255) / 256;
    int gx = ((Nn + 127) / 128) * 2;   // 1564: (mb, nb) pairs

    k_agg1<<<ab, 256, 0, stream>>>(xb, agg1, rowptr, srcl);
    k_gemm1<<<gx, 256, 0, stream>>>(agg1, xb, Wt1, b1, flag, acat_ws);
    k_agg2<<<ab, 256, 0, stream>>>(rowptr, srcl, acat_ws);
    k_gemm2<<<gx, 256, 0, stream>>>(Wt2, b2, flag, acat_ws, d_out);
}

// Round 11
// 376.583 us; speedup vs baseline: 1.0306x; 1.0278x over previous
//
#include <hip/hip_runtime.h>

#define Nn 100000
#define Ee 600000
#define Fin 128
#define Hd  256
#define NB  ((Nn + 1023) / 1024)   // 98 scan blocks
#define CB  12500                  // convert blocks: Nn*Fin/4/256
#define PB  768                    // prep blocks
#define EB  ((Ee + 255) / 256)     // edge blocks

typedef __attribute__((ext_vector_type(8))) short short8;
typedef __attribute__((ext_vector_type(4))) float floatx4;

__device__ __forceinline__ float bf2f(unsigned short h) {
    return __uint_as_float(((unsigned int)h) << 16);
}
__device__ __forceinline__ unsigned short f2bf(float f) {
    unsigned int u = __float_as_uint(f);
    u += 0x7FFFu + ((u >> 16) & 1u);   // round-to-nearest-even
    return (unsigned short)(u >> 16);
}
__device__ __forceinline__ float loadf(const void* p, int i, int f32) {
    return f32 ? ((const float*)p)[i] : bf2f(((const unsigned short*)p)[i]);
}
__device__ __forceinline__ void gload_lds16(const void* g, void* lds) {
    __builtin_amdgcn_global_load_lds((const __attribute__((address_space(1))) void*)g,
                                     (__attribute__((address_space(3))) void*)lds,
                                     16, 0, 0);
}

__device__ __forceinline__ void get_edge(const int* __restrict__ ei, int is64, int e,
                                         int& s, int& d) {
    if (is64) { s = ei[2 * e]; d = ei[2 * (Ee + e)]; }
    else      { s = ei[e];     d = ei[Ee + e]; }
}

// ---- fused: runtime probes (wave-parallel) + cnt/cur zero ----
__global__ void k_init(const unsigned int* __restrict__ ei,
                       const unsigned short* __restrict__ xu,
                       int* __restrict__ flag, int* __restrict__ cnt) {
    int i = blockIdx.x * 256 + threadIdx.x;
    if (i < 2 * Nn) cnt[i] = 0;            // cnt and cur are contiguous
    if (blockIdx.x == 0 && threadIdx.x < 64) {
        int l = threadIdx.x;
        unsigned hi = (l < 32) ? ei[2 * l + 1] : 0u;      // high halves of first 32 int64
        unsigned long long nz = __ballot(hi != 0u);
        int big = 0;
#pragma unroll
        for (int j = 0; j < 4; j++) {                     // even ushorts 0..510
            unsigned u = xu[l * 8 + j * 2];
            if (((u >> 7) & 0xFFu) >= 0xC0u) big = 1;
        }
        unsigned long long bb = __ballot(big != 0);
        if (l == 0) { flag[0] = (nz == 0ull) ? 1 : 0; flag[1] = (bb != 0ull) ? 1 : 0; }
    }
}

// ---- fused: x->xb convert | weight pre-transpose | edge degree count ----
__global__ void k_pre(const void* __restrict__ x, unsigned short* __restrict__ xb,
                      const void* __restrict__ Wl1, const void* __restrict__ Wr1,
                      const void* __restrict__ Wl2, const void* __restrict__ Wr2,
                      unsigned short* __restrict__ Wt1, unsigned short* __restrict__ Wt2,
                      const int* __restrict__ ei, int* __restrict__ cnt,
                      const int* __restrict__ flag) {
    int bid = blockIdx.x;
    if (bid < CB) {
        int i = (bid * 256 + threadIdx.x) * 4;
        if (i >= Nn * Fin) return;
        if (flag[1]) {
            float4 v = ((const float4*)x)[i >> 2];
            ushort4 u;
            u.x = f2bf(v.x); u.y = f2bf(v.y); u.z = f2bf(v.z); u.w = f2bf(v.w);
            ((ushort4*)xb)[i >> 2] = u;
        } else {
            ((ushort4*)xb)[i >> 2] = ((const ushort4*)x)[i >> 2];
        }
    } else if (bid < CB + PB) {
        int f32 = flag[1];
        int tid = (bid - CB) * 256 + threadIdx.x;
        if (tid < 256 * 256) {
            int n = tid >> 8, k = tid & 255;
            float v = (k < 128) ? loadf(Wl1, k * 256 + n, f32) : loadf(Wr1, (k - 128) * 256 + n, f32);
            Wt1[n * 256 + k] = f2bf(v);
        }
        int t2 = tid - 256 * 256;
        if (t2 >= 0 && t2 < 256 * 512) {
            int n = t2 >> 9, k = t2 & 511;
            float v = (k < 256) ? loadf(Wl2, k * 256 + n, f32) : loadf(Wr2, (k - 256) * 256 + n, f32);
            Wt2[n * 512 + k] = f2bf(v);
        }
    } else {
        int e = (bid - CB - PB) * 256 + threadIdx.x;
        if (e >= Ee) return;
        int is64 = flag[0], s, d;
        get_edge(ei, is64, e, s, d);
        atomicAdd(&cnt[d], 1);
    }
}

// hierarchical scan: k_bsum -> k_bscan -> k_rowptr (all coalesced int4)
__global__ void k_bsum(const int* __restrict__ cnt, int* __restrict__ bsum) {
    __shared__ int red[256];
    int b = blockIdx.x, t = threadIdx.x;
    int i = b * 1024 + t * 4;
    int s = 0;
    if (i + 3 < Nn) {
        int4 v = *reinterpret_cast<const int4*>(cnt + i);
        s = v.x + v.y + v.z + v.w;
    } else {
        for (int j = 0; j < 4; j++) if (i + j < Nn) s += cnt[i + j];
    }
    red[t] = s;
    __syncthreads();
    for (int off = 128; off > 0; off >>= 1) {
        if (t < off) red[t] += red[t + off];
        __syncthreads();
    }
    if (t == 0) bsum[b] = red[0];
}

__global__ void k_bscan(const int* __restrict__ bsum, int* __restrict__ bpre,
                        int* __restrict__ rowptr) {
    __shared__ int sc[128];
    int t = threadIdx.x;
    int v = (t < NB) ? bsum[t] : 0;
    sc[t] = v;
    __syncthreads();
    for (int off = 1; off < 128; off <<= 1) {
        int add = (t >= off) ? sc[t - off] : 0;
        __syncthreads();
        sc[t] += add;
        __syncthreads();
    }
    if (t < NB) bpre[t] = sc[t] - v;          // exclusive prefix
    if (t == 127) rowptr[Nn] = sc[127];       // grand total (== Ee)
}

__global__ void k_rowptr(const int* __restrict__ cnt, const int* __restrict__ bpre,
                         int* __restrict__ rowptr) {
    __shared__ int sc[256];
    int b = blockIdx.x, t = threadIdx.x;
    int i = b * 1024 + t * 4;
    int4 c = make_int4(0, 0, 0, 0);
    if (i + 3 < Nn) {
        c = *reinterpret_cast<const int4*>(cnt + i);
    } else {
        if (i     < Nn) c.x = cnt[i];
        if (i + 1 < Nn) c.y = cnt[i + 1];
        if (i + 2 < Nn) c.z = cnt[i + 2];
        if (i + 3 < Nn) c.w = cnt[i + 3];
    }
    int s = c.x + c.y + c.z + c.w;
    sc[t] = s;
    __syncthreads();
    for (int off = 1; off < 256; off <<= 1) {
        int add = (t >= off) ? sc[t - off] : 0;
        __syncthreads();
        sc[t] += add;
        __syncthreads();
    }
    int p = bpre[b] + sc[t] - s;   // exclusive prefix of element i
    int4 r;
    r.x = p;
    r.y = r.x + c.x;
    r.z = r.y + c.y;
    r.w = r.z + c.z;
    if (i + 3 < Nn) {
        *reinterpret_cast<int4*>(rowptr + i) = r;
    } else {
        if (i     < Nn) rowptr[i]     = r.x;
        if (i + 1 < Nn) rowptr[i + 1] = r.y;
        if (i + 2 < Nn) rowptr[i + 2] = r.z;
        if (i + 3 < Nn) rowptr[i + 3] = r.w;
    }
}

__global__ void k_fill(const int* __restrict__ ei, const int* __restrict__ flag,
                       const int* __restrict__ rowptr, int* __restrict__ cur,
                       int* __restrict__ srcl) {
    int e = blockIdx.x * 256 + threadIdx.x;
    if (e >= Ee) return;
    int is64 = flag[0], s, d;
    get_edge(ei, is64, e, s, d);
    int pos = atomicAdd(&cur[d], 1);
    srcl[rowptr[d] + pos] = s;
}

// ---- gather-based mean aggregation: one wave per node, 8-deep MLP ----
template <int F, int SIN, int SOUT>
__device__ __forceinline__ void agg_body(const unsigned short* __restrict__ X,
                                         unsigned short* __restrict__ O,
                                         const int* __restrict__ rowptr,
                                         const int* __restrict__ srcl) {
    int gw = (blockIdx.x * blockDim.x + threadIdx.x) >> 6;
    int lane = threadIdx.x & 63;
    if (gw >= Nn) return;
    int b = rowptr[gw], e = rowptr[gw + 1];
    constexpr int C = F / 64;
    float acc[C] = {};
    if (e > b) {
        int last = e - 1;
        for (int i = b; i < e; i += 8) {
            int sv[8];
            float w[8];
#pragma unroll
            for (int j = 0; j < 8; j++) {
                int id = i + j;
                sv[j] = srcl[id < last ? id : last];
                w[j] = (id < e) ? 1.f : 0.f;
            }
            if constexpr (C == 2) {
                ushort2 u[8];
#pragma unroll
                for (int j = 0; j < 8; j++)
                    u[j] = *reinterpret_cast<const ushort2*>(X + (size_t)sv[j] * SIN + lane * 2);
#pragma unroll
                for (int j = 0; j < 8; j++) {
                    acc[0] = fmaf(w[j], bf2f(u[j].x), acc[0]);
                    acc[1] = fmaf(w[j], bf2f(u[j].y), acc[1]);
                }
            } else {
                ushort4 u[8];
#pragma unroll
                for (int j = 0; j < 8; j++)
                    u[j] = *reinterpret_cast<const ushort4*>(X + (size_t)sv[j] * SIN + lane * 4);
#pragma unroll
                for (int j = 0; j < 8; j++) {
                    acc[0] = fmaf(w[j], bf2f(u[j].x), acc[0]);
                    acc[1] = fmaf(w[j], bf2f(u[j].y), acc[1]);
                    acc[2] = fmaf(w[j], bf2f(u[j].z), acc[2]);
                    acc[3] = fmaf(w[j], bf2f(u[j].w), acc[3]);
                }
            }
        }
    }
    float inv = 1.f / (float)max(e - b, 1);
    unsigned short* op = O + (size_t)gw * SOUT + lane * C;
    if constexpr (C == 2) {
        ushort2 u; u.x = f2bf(acc[0] * inv); u.y = f2bf(acc[1] * inv);
        *reinterpret_cast<ushort2*>(op) = u;
    } else {
        ushort4 u;
        u.x = f2bf(acc[0] * inv); u.y = f2bf(acc[1] * inv);
        u.z = f2bf(acc[2] * inv); u.w = f2bf(acc[3] * inv);
        *reinterpret_cast<ushort4*>(op) = u;
    }
}

__global__ void k_agg1(const unsigned short* __restrict__ xb, unsigned short* __restrict__ agg1,
                       const int* __restrict__ rowptr, const int* __restrict__ srcl) {
    agg_body<Fin, Fin, Fin>(xb, agg1, rowptr, srcl);
}

__global__ void k_agg2(const int* __restrict__ rowptr, const int* __restrict__ srcl,
                       unsigned short* __restrict__ acat_ws) {
    agg_body<Hd, 512, 512>(acat_ws + 256, acat_ws, rowptr, srcl);
}

// ---- MFMA GEMM core (R5/R8-proven fixed point): BM=128 x BN=256, 8 waves,
// BK=64, single-buffered, 2 barriers/kb, 0 K-loop bank conflicts.
// Four restructures nulled or regressed against this: R3 (vmcnt dbuf),
// R7 (1-barrier dbuf), R9 (triple-buffer counted vmcnt, 1 blk/CU),
// R10 (128x128 split: FETCH 2x — XCD round-robin defeats pair L2 sharing).
// Implicit 3-blocks/CU wave overlap covers the stage drain (m99/m131).
template <int KT, int K1, int S1, int S2>
__device__ __forceinline__ void gemm_core_lds(const unsigned short* __restrict__ A1,
                                              const unsigned short* __restrict__ A2,
                                              const unsigned short* __restrict__ Wt,
                                              floatx4 (&acc)[4][4],
                                              unsigned short* sA, unsigned short* sB,
                                              int m_base) {
    const int tid = threadIdx.x;
    const int lane = tid & 63, wid = tid >> 6;
    const int wm = wid & 1, wn = wid >> 1;
    const int quad = lane >> 4, l16 = lane & 15;
    const int n_base = wn * 64;
    const int rs = tid >> 3;       // row-octet owner: 64 rows per 512-thread pass
    const int cs = tid & 7;        // k-chunk slot (8 shorts each)

    for (int kb = 0; kb < KT; kb += 64) {
        __syncthreads();
        // stage A: 128 rows x 64 k, pre-swizzled global source -> linear LDS dest
#pragma unroll
        for (int i = 0; i < 2; i++) {
            int r = i * 64 + rs;
            int gk = kb + ((cs ^ (r & 7)) << 3);
            int m = m_base + r; if (m >= Nn) m = Nn - 1;
            const unsigned short* gp = (gk < K1)
                ? A1 + (size_t)m * S1 + gk
                : A2 + (size_t)m * S2 + (gk - K1);
            gload_lds16(gp, sA + i * 4096 + wid * 512);
        }
        // stage B: 256 rows x 64 k, same swizzle scheme
#pragma unroll
        for (int i = 0; i < 4; i++) {
            int n = i * 64 + rs;
            int gk = kb + ((cs ^ (n & 7)) << 3);
            gload_lds16(Wt + (size_t)n * KT + gk, sB + i * 4096 + wid * 512);
        }
        __syncthreads();
#pragma unroll
        for (int ks = 0; ks < 64; ks += 32) {
            short8 a[4], b[4];
            int q = (ks >> 3) + quad;
#pragma unroll
            for (int mt = 0; mt < 4; mt++) {
                int r = wm * 64 + mt * 16 + l16;
                a[mt] = *reinterpret_cast<const short8*>(
                    sA + r * 64 + ((q ^ (l16 & 7)) << 3));
            }
#pragma unroll
            for (int nt = 0; nt < 4; nt++) {
                int n = n_base + nt * 16 + l16;
                b[nt] = *reinterpret_cast<const short8*>(
                    sB + n * 64 + ((q ^ (l16 & 7)) << 3));
            }
#pragma unroll
            for (int mt = 0; mt < 4; mt++)
#pragma unroll
                for (int nt = 0; nt < 4; nt++)
                    acc[mt][nt] = __builtin_amdgcn_mfma_f32_16x16x32_bf16(a[mt], b[nt], acc[mt][nt], 0, 0, 0);
        }
    }
}

// layer 1: h = relu([agg1|xb] @ Wt1 + b1) -> Acat[:,256:512) (bf16)
// Coalesced epilogue via 32 KB LDS bounce (sB reused); WRITE-amp fix (R7: 145->100MB).
__global__ __launch_bounds__(512) void k_gemm1(const unsigned short* __restrict__ agg1,
                                               const unsigned short* __restrict__ xb,
                                               const unsigned short* __restrict__ Wt1,
                                               const void* __restrict__ bias,
                                               const int* __restrict__ flag,
                                               unsigned short* __restrict__ acat_ws) {
    __shared__ unsigned short sA[8192];
    __shared__ unsigned short sB[16384];
    int f32 = flag[1];
    int tid = threadIdx.x;
    int wid = tid >> 6, lane = tid & 63;
    int wm = wid & 1, wn = wid >> 1;
    int quad = lane >> 4, l16 = lane & 15;
    int m_base = blockIdx.x * 128;
    floatx4 acc[4][4] = {};
    gemm_core_lds<256, 128, 128, 128>(agg1, xb, Wt1, acc, sA, sB, m_base);
#pragma unroll
    for (int p = 0; p < 2; p++) {
        __syncthreads();                       // sB free (K-loop / prev pass done)
        if (wm == p) {
#pragma unroll
            for (int nt = 0; nt < 4; nt++) {
                int n = wn * 64 + nt * 16 + l16;
                float bv = loadf(bias, n, f32);
#pragma unroll
                for (int mt = 0; mt < 4; mt++) {
#pragma unroll
                    for (int r = 0; r < 4; r++) {
                        float v = acc[mt][nt][r] + bv;
                        v = v > 0.f ? v : 0.f;
                        sB[(mt * 16 + quad * 4 + r) * 256 + n] = f2bf(v);
                    }
                }
            }
        }
        __syncthreads();
#pragma unroll
        for (int rnd = 0; rnd < 4; rnd++) {
            int rl = rnd * 16 + (tid >> 5);
            int m = m_base + p * 64 + rl;
            if (m < Nn)
                *reinterpret_cast<short8*>(acat_ws + (size_t)m * 512 + 256 + (tid & 31) * 8) =
                    *reinterpret_cast<const short8*>(sB + rl * 256 + (tid & 31) * 8);
        }
    }
}

// layer 2: out = [agg2|h] @ Wt2 + b2. Acat row = [agg|h] contiguous 512-k
// stream, so K1=512 makes the A2 branch compile-time dead.
__global__ __launch_bounds__(512) void k_gemm2(const unsigned short* __restrict__ Wt2,
                                               const void* __restrict__ bias,
                                               const int* __restrict__ flag,
                                               const unsigned short* __restrict__ acat_ws,
                                               void* __restrict__ out) {
    __shared__ unsigned short sA[8192];
    __shared__ unsigned short sB[16384];
    int f32 = flag[1];
    int tid = threadIdx.x;
    int wid = tid >> 6, lane = tid & 63;
    int wm = wid & 1, wn = wid >> 1;
    int quad = lane >> 4, l16 = lane & 15;
    int m_base = blockIdx.x * 128;
    floatx4 acc[4][4] = {};
    gemm_core_lds<512, 512, 512, 512>(acat_ws, acat_ws, Wt2, acc, sA, sB, m_base);
    float* sF = (float*)sB;                    // 32 rows x 256 f32 = 32 KB
#pragma unroll
    for (int q = 0; q < 4; q++) {
        __syncthreads();
        if (wm == (q >> 1)) {
#pragma unroll
            for (int nt = 0; nt < 4; nt++) {
                int n = wn * 64 + nt * 16 + l16;
                float bv = loadf(bias, n, f32);
#pragma unroll
                for (int mt2 = 0; mt2 < 2; mt2++) {
                    int mt = (q & 1) * 2 + mt2;
#pragma unroll
                    for (int r = 0; r < 4; r++)
                        sF[(mt2 * 16 + quad * 4 + r) * 256 + n] = acc[mt][nt][r] + bv;
                }
            }
        }
        __syncthreads();
#pragma unroll
        for (int rnd = 0; rnd < 2; rnd++) {
            int rl = rnd * 16 + (tid >> 5);
            int m = m_base + q * 32 + rl;
            if (m < Nn) {
                if (f32) {
                    float4* dst = (float4*)((float*)out + (size_t)m * 256) + (tid & 31) * 2;
                    const float4* src = (const float4*)(sF + rl * 256) + (tid & 31) * 2;
                    dst[0] = src[0];
                    dst[1] = src[1];
                } else {
                    const float* src = sF + rl * 256 + (tid & 31) * 8;
                    short8 pk;
#pragma unroll
                    for (int j = 0; j < 8; j++)
                        ((unsigned short*)&pk)[j] = f2bf(src[j]);
                    *reinterpret_cast<short8*>((unsigned short*)out + (size_t)m * 256 + (tid & 31) * 8) = pk;
                }
            }
        }
    }
}

extern "C" void kernel_launch(void* const* d_in, const int* in_sizes, int n_in,
                              void* d_out, int out_size, void* d_ws, size_t ws_size,
                              hipStream_t stream) {
    const void* x   = d_in[0];
    const int*  ei  = (const int*)d_in[1];
    const void* Wl1 = d_in[2];
    const void* Wr1 = d_in[3];
    const void* b1  = d_in[4];
    const void* Wl2 = d_in[5];
    const void* Wr2 = d_in[6];
    const void* b2  = d_in[7];

    char* ws = (char*)d_ws;
    size_t off_cnt    = 0;
    size_t off_cur    = off_cnt + (size_t)Nn * 4;
    size_t off_rowptr = off_cur + (size_t)Nn * 4;
    size_t off_srcl   = off_rowptr + (size_t)(Nn + 4) * 4;
    size_t off_flag   = off_srcl + (size_t)Ee * 4;
    size_t off_bsum   = ((off_flag + 8 + 255) / 256) * 256;   // NB ints
    size_t off_bpre   = off_bsum + 128 * 4;                   // NB ints
    size_t off_wt1    = off_bpre + 128 * 4;
    size_t off_wt2    = off_wt1 + 256 * 256 * 2;
    size_t off_xb     = off_wt2 + 256 * 512 * 2;
    size_t off_agg1   = off_xb + (size_t)Nn * Fin * 2;
    size_t off_acat   = off_agg1 + (size_t)Nn * Fin * 2;

    int*            cnt     = (int*)(ws + off_cnt);
    int*            cur     = (int*)(ws + off_cur);
    int*            rowptr  = (int*)(ws + off_rowptr);
    int*            srcl    = (int*)(ws + off_srcl);
    int*            flag    = (int*)(ws + off_flag);
    int*            bsum    = (int*)(ws + off_bsum);
    int*            bpre    = (int*)(ws + off_bpre);
    unsigned short* Wt1     = (unsigned short*)(ws + off_wt1);
    unsigned short* Wt2     = (unsigned short*)(ws + off_wt2);
    unsigned short* xb      = (unsigned short*)(ws + off_xb);
    unsigned short* agg1    = (unsigned short*)(ws + off_agg1);
    unsigned short* acat_ws = (unsigned short*)(ws + off_acat);

    k_init<<<(2 * Nn + 255) / 256, 256, 0, stream>>>((const unsigned int*)ei,
                                                     (const unsigned short*)x, flag, cnt);
    k_pre<<<CB + PB + EB, 256, 0, stream>>>(x, xb, Wl1, Wr1, Wl2, Wr2, Wt1, Wt2,
                                            ei, cnt, flag);
    k_bsum<<<NB, 256, 0, stream>>>(cnt, bsum);
    k_bscan<<<1, 128, 0, stream>>>(bsum, bpre, rowptr);
    k_rowptr<<<NB, 256, 0, stream>>>(cnt, bpre, rowptr);
    k_fill<<<EB, 256, 0, stream>>>(ei, flag, rowptr, cur, srcl);

    int ab = (Nn * 64 + 255) / 256;
    int gx = (Nn + 127) / 128;

    k_agg1<<<ab, 256, 0, stream>>>(xb, agg1, rowptr, srcl);
    k_gemm1<<<gx, 512, 0, stream>>>(agg1, xb, Wt1, b1, flag, acat_ws);
    k_agg2<<<ab, 256, 0, stream>>>(rowptr, srcl, acat_ws);
    k_gemm2<<<gx, 512, 0, stream>>>(Wt2, b2, flag, acat_ws, d_out);
}